// Round 8
// baseline (142.778 us; speedup 1.0000x reference)
//
#include <hip/hip_runtime.h>
#include <cstdint>
#include <cstddef>

#define NROWS 32768   // 128 * 256 rows of D=1024
#define DDIM  1024
#define TPB   256     // 4 waves/block, 1 row per wave, 16 elems/thread
#define ROWS_PER_BLOCK 4

// ---------------- Threefry-2x32 (JAX/Random123) ----------------

__device__ __forceinline__ uint32_t rotl32(uint32_t x, uint32_t r) {
#if __has_builtin(__builtin_amdgcn_alignbit)
  return __builtin_amdgcn_alignbit(x, x, 32u - r);   // one v_alignbit_b32
#else
  return (x << r) | (x >> (32u - r));
#endif
}

// One threefry2x32 block, counter (0,c), caller passes x1init = c + k1.
// Returns x0 ^ x1 (JAX partitionable fold). Branch-free, 2-op rounds + add3.
__device__ __forceinline__ uint32_t threefry_fold(uint32_t k0, uint32_t k1,
                                                  uint32_t x1init) {
  const uint32_t ks2 = k0 ^ k1 ^ 0x1BD11BDAu;
  uint32_t x1 = x1init;
  uint32_t x0 = k0 + x1;
  x1 = rotl32(x1, 13) ^ x0;
  x0 += x1; x1 = rotl32(x1, 15) ^ x0;
  x0 += x1; x1 = rotl32(x1, 26) ^ x0;
  x0 += x1; x1 = rotl32(x1,  6) ^ x0;
#define TF_GROUP(rA, rB, rC, rD, kA, kB)                  \
  x1 += (kB); x0 = (x0 + (kA)) + x1;                      \
  x1 = rotl32(x1, rA) ^ x0;                               \
  x0 += x1; x1 = rotl32(x1, rB) ^ x0;                     \
  x0 += x1; x1 = rotl32(x1, rC) ^ x0;                     \
  x0 += x1; x1 = rotl32(x1, rD) ^ x0;
  TF_GROUP(17, 29, 16, 24, k1,  ks2 + 1u)
  TF_GROUP(13, 15, 26,  6, ks2, k0  + 2u)
  TF_GROUP(17, 29, 16, 24, k0,  k1  + 3u)
  TF_GROUP(13, 15, 26,  6, k1,  ks2 + 4u)
#undef TF_GROUP
  x0 += ks2;
  x1 += k0 + 5u;
  return x0 ^ x1;
}

__device__ __forceinline__ float fast_sqrtf(float x) {
#if __has_builtin(__builtin_amdgcn_sqrtf)
  return __builtin_amdgcn_sqrtf(x);   // raw v_sqrt_f32
#else
  return sqrtf(x);
#endif
}

// ---- branch-free sqrt(2)*erfinv(uniform(lo,1)) ----
// u from bits (XLA-exact value, single rounding); l = log2(1-u^2).
// Warm poly Q(l) (deg-4, recentered in l; == R5 poly to ~1e-5).
// Cold poly C(v), v = sqrt(-ln2*l) (deg-4, recentered in v; == R4 cold).
// Select by l > -7.2134752 (w<5) with cndmask. No exec-mask branches at all.
// Verified algebra: Q(0)=1.2541608=sqrt(2pi)/2; Q(-7.2134752)=2.94278 vs
// C(sqrt(5))=2.93970 (seam, both fits' ~1e-3 error); C(3)=4.0064341=d0.

__device__ __forceinline__ float bits_to_normal(uint32_t bits) {
  const float lo = -0.99999994f;               // nextafter(-1,0)
  float fn = (float)(bits >> 9);               // v_cvt_f32_u32, exact (<2^23)
  float u  = fmaf(fn, 0x1p-22f, lo);           // == XLA bitcast path
  float t  = fmaf(-u, u, 1.0f);                // 1 - u^2 > 0
  float l  = __log2f(t);                       // v_log_f32, l <= 0

  // warm: Q(l), l in (-7.2134752, 0]
  float pw = 7.1356157e-5f;
  pw = fmaf(pw, l, 1.6199280e-3f);
  pw = fmaf(pw, l, 9.1199371e-3f);
  pw = fmaf(pw, l, -2.2581228e-1f);
  pw = fmaf(pw, l, 1.2541608f);

  // cold: C(v), v = sqrt(w) in [sqrt(5), 4)
  float v = fast_sqrtf(-0.69314718f * l);
  float pc = 8.1169400e-3f;
  pc = fmaf(pc, v, -1.0818307e-1f);
  pc = fmaf(pc, v, 5.4868148e-1f);
  pc = fmaf(pc, v, 1.6880551e-1f);
  pc = fmaf(pc, v, 8.2535511e-1f);

  float p = (l > -7.2134752f) ? pw : pc;       // v_cmp + v_cndmask
  return p * u;
}

// ---- fused kernel: 1 wave == 1 row, no LDS/barrier, fully branch-free body.
// Phase-split per 4-elem group: 8 threefry folds, then 8 normals, then 4
// fused-affine stores -- one scheduling region, 8+ independent chains.

__global__ __launch_bounds__(TPB) void NormalAugmenter_kernel(
    const float* __restrict__ in, float* __restrict__ out,
    uint32_t k1a, uint32_t k1b, uint32_t k2a, uint32_t k2b) {
  const uint32_t wave = threadIdx.x >> 6;               // 0..3
  const uint32_t lane = threadIdx.x & 63u;
  const uint32_t row  = blockIdx.x * ROWS_PER_BLOCK + wave;
  const size_t rowoff = (size_t)row * DDIM;
  const float4* vin  = reinterpret_cast<const float4*>(in + rowoff);
  float4*       vout = reinterpret_cast<float4*>(out + rowoff);

  float4 v0 = vin[lane];
  float4 v1 = vin[lane + 64u];
  float4 v2 = vin[lane + 128u];
  float4 v3 = vin[lane + 192u];
  float x[16] = {v0.x,v0.y,v0.z,v0.w, v1.x,v1.y,v1.z,v1.w,
                 v2.x,v2.y,v2.z,v2.w, v3.x,v3.y,v3.z,v3.w};

  // ---- row stats: in-wave reduction only
  float s = 0.0f, q = 0.0f;
  #pragma unroll
  for (int i = 0; i < 16; ++i) { s += x[i]; q = fmaf(x[i], x[i], q); }
  #pragma unroll
  for (int off = 32; off >= 1; off >>= 1) {
    s += __shfl_xor(s, off, 64);
    q += __shfl_xor(q, off, 64);
  }

  const float invD = 1.0f / (float)DDIM;
  const float mean = s * invD;
  float M2 = fmaf(-s, mean, q);                         // q - s^2/D
  M2 = fmaxf(M2, 0.0f);
  const float std_u = fast_sqrtf(M2 * (1.0f / (DDIM - 1))); // unbiased std
  const float rstd  = rsqrtf(fmaf(M2, invD, 1e-5f));    // 1/sqrt(var_b+eps)
  const float hstd  = 0.5f * std_u;
  const float hmean = 0.5f * mean;
  const float noff  = -mean * rstd;

  // threefry x1-init bases for streams A and B (counter + key1 prefolded)
  const uint32_t cb = row * (uint32_t)DDIM + lane * 4u;
  const uint32_t dA = cb + k1b;
  const uint32_t dB = cb + k2b;

  #pragma unroll
  for (uint32_t g = 0; g < 4; ++g) {
    const uint32_t gofs = g * 256u;
    // ---- P1: 8 independent threefry chains (branch-free block)
    uint32_t bA0 = threefry_fold(k1a, k1b, dA + gofs + 0u);
    uint32_t bA1 = threefry_fold(k1a, k1b, dA + gofs + 1u);
    uint32_t bA2 = threefry_fold(k1a, k1b, dA + gofs + 2u);
    uint32_t bA3 = threefry_fold(k1a, k1b, dA + gofs + 3u);
    uint32_t bB0 = threefry_fold(k2a, k2b, dB + gofs + 0u);
    uint32_t bB1 = threefry_fold(k2a, k2b, dB + gofs + 1u);
    uint32_t bB2 = threefry_fold(k2a, k2b, dB + gofs + 2u);
    uint32_t bB3 = threefry_fold(k2a, k2b, dB + gofs + 3u);
    // ---- P2+P3: 8 branch-free normals
    float eA0 = bits_to_normal(bA0), eA1 = bits_to_normal(bA1);
    float eA2 = bits_to_normal(bA2), eA3 = bits_to_normal(bA3);
    float eB0 = bits_to_normal(bB0), eB1 = bits_to_normal(bB1);
    float eB2 = bits_to_normal(bB2), eB3 = bits_to_normal(bB3);
    // ---- P4: fused affine, one float4 store per group
    const float x0g = x[4*g+0], x1g = x[4*g+1], x2g = x[4*g+2], x3g = x[4*g+3];
    float4 o;
    o.x = fmaf(fmaf(hstd, eA0, 0.5f), fmaf(x0g, rstd, noff), fmaf(hstd, eB0, hmean));
    o.y = fmaf(fmaf(hstd, eA1, 0.5f), fmaf(x1g, rstd, noff), fmaf(hstd, eB1, hmean));
    o.z = fmaf(fmaf(hstd, eA2, 0.5f), fmaf(x2g, rstd, noff), fmaf(hstd, eB2, hmean));
    o.w = fmaf(fmaf(hstd, eA3, 0.5f), fmaf(x3g, rstd, noff), fmaf(hstd, eB3, hmean));
    vout[lane + 64u * g] = o;
  }
}

// ---------------- host side ----------------

static void tf_host(uint32_t k0, uint32_t k1, uint32_t c0, uint32_t c1,
                    uint32_t& o0, uint32_t& o1) {
  auto rot = [](uint32_t x, uint32_t r) { return (x << r) | (x >> (32u - r)); };
  const uint32_t ks[3] = {k0, k1, k0 ^ k1 ^ 0x1BD11BDAu};
  const uint32_t rots[2][4] = {{13u,15u,26u,6u},{17u,29u,16u,24u}};
  uint32_t x0 = c0 + k0, x1 = c1 + k1;
  for (int i = 0; i < 5; ++i) {
    const uint32_t* rr = rots[i & 1];
    for (int j = 0; j < 4; ++j) { x0 += x1; x1 = rot(x1, rr[j]); x1 ^= x0; }
    x0 += ks[(i + 1) % 3];
    x1 += ks[(i + 2) % 3] + (uint32_t)(i + 1);
  }
  o0 = x0; o1 = x1;
}

extern "C" void kernel_launch(void* const* d_in, const int* in_sizes, int n_in,
                              void* d_out, int out_size, void* d_ws, size_t ws_size,
                              hipStream_t stream) {
  const float* in = (const float*)d_in[0];
  float* out = (float*)d_out;

  // jax.random.key(42) -> (0,42); split (threefry_partitionable):
  // k1 = threefry((0,42),(0,0)), k2 = threefry((0,42),(0,1))
  uint32_t k1a, k1b, k2a, k2b;
  tf_host(0u, 42u, 0u, 0u, k1a, k1b);
  tf_host(0u, 42u, 0u, 1u, k2a, k2b);

  NormalAugmenter_kernel<<<NROWS / ROWS_PER_BLOCK, TPB, 0, stream>>>(
      in, out, k1a, k1b, k2a, k2b);
}

// Round 9
// 139.398 us; speedup vs baseline: 1.0242x; 1.0242x over previous
//
#include <hip/hip_runtime.h>
#include <cstdint>
#include <cstddef>

#define NROWS 32768   // 128 * 256 rows of D=1024
#define DDIM  1024
#define TPB   256     // 4 waves/block, 1 row per wave, 16 elems/thread
#define ROWS_PER_BLOCK 4

// ---------------- Threefry-2x32, add3-friendly, XOR-folded ----------------

__device__ __forceinline__ uint32_t rotl32(uint32_t x, uint32_t r) {
#if __has_builtin(__builtin_amdgcn_alignbit)
  return __builtin_amdgcn_alignbit(x, x, 32u - r);   // one v_alignbit_b32
#else
  return (x << r) | (x >> (32u - r));
#endif
}

// One threefry2x32 block with counter (0,c); returns x0^x1 (JAX partitionable fold).
__device__ __forceinline__ uint32_t threefry_fold(uint32_t k0, uint32_t k1, uint32_t c) {
  const uint32_t ks2 = k0 ^ k1 ^ 0x1BD11BDAu;
  uint32_t x1 = c + k1;
  uint32_t x0 = k0 + x1;
  x1 = rotl32(x1, 13) ^ x0;
  x0 += x1; x1 = rotl32(x1, 15) ^ x0;
  x0 += x1; x1 = rotl32(x1, 26) ^ x0;
  x0 += x1; x1 = rotl32(x1,  6) ^ x0;
#define TF_GROUP(rA, rB, rC, rD, kA, kB)                  \
  x1 += (kB); x0 = (x0 + (kA)) + x1;                      \
  x1 = rotl32(x1, rA) ^ x0;                               \
  x0 += x1; x1 = rotl32(x1, rB) ^ x0;                     \
  x0 += x1; x1 = rotl32(x1, rC) ^ x0;                     \
  x0 += x1; x1 = rotl32(x1, rD) ^ x0;
  TF_GROUP(17, 29, 16, 24, k1,  ks2 + 1u)
  TF_GROUP(13, 15, 26,  6, ks2, k0  + 2u)
  TF_GROUP(17, 29, 16, 24, k0,  k1  + 3u)
  TF_GROUP(13, 15, 26,  6, k1,  ks2 + 4u)
#undef TF_GROUP
  x0 += ks2;
  x1 += k0 + 5u;
  return x0 ^ x1;
}

// ---- bits -> sqrt(2)*erfinv(uniform(lo,1)), poly evaluated directly in ----
// l = log2(1-u^2); Giles warm poly re-centered in l with coeffs scaled by
// (-ln2)^k; deg-4 both branches, sqrt(2)-prefolded. Validated: absmax 0.031.

__device__ __forceinline__ float bits_to_normal(uint32_t bits) {
  const float lo = -0.99999994f;               // nextafter(-1,0)
  float fn = (float)(bits >> 9);               // v_cvt_f32_u32, exact (<2^23)
  float u  = fmaf(fn, 0x1p-22f, lo);           // == XLA bitcast path, 1 rounding
  float t  = fmaf(-u, u, 1.0f);                // 1 - u^2 > 0
  float l  = __log2f(t);                       // v_log_f32
  float p;
  if (__builtin_expect(l > -7.2134752f, 1)) {  // w < 5 (warm)
    float z = l + 3.6067376f;                  // z = l + 2.5/ln2
    p = 7.1356157e-5f;
    p = fmaf(p, z, 5.9047624e-4f);
    p = fmaf(p, z, -2.8385851e-3f);
    p = fmaf(p, z, -2.4177163e-1f);
    p = fmaf(p, z, 2.1233142f);
  } else {                                     // cold: |u|>0.9966, ~0.34%
    float w = -0.69314718f * l;
    float zz = sqrtf(w) - 3.0f;
    p = 8.1169400e-3f;
    p = fmaf(p, zz, -1.0779791e-2f);
    p = fmaf(p, zz, 1.3348601e-2f);
    p = fmaf(p, zz, 1.4165810f);
    p = fmaf(p, zz, 4.0064342f);
  }
  return p * u;
}

// ---- fused kernel: 1 wave == 1 row, no LDS/barrier, fully unrolled (R5 best:
// 139.1 us). Reverted from R8 branch-free variant (142.8) -- divergence is
// cheaper than always-executing both polys.

__global__ __launch_bounds__(TPB) void NormalAugmenter_kernel(
    const float* __restrict__ in, float* __restrict__ out,
    uint32_t k1a, uint32_t k1b, uint32_t k2a, uint32_t k2b) {
  const uint32_t wave = threadIdx.x >> 6;               // 0..3
  const uint32_t lane = threadIdx.x & 63u;
  const uint32_t row  = blockIdx.x * ROWS_PER_BLOCK + wave;
  const size_t rowoff = (size_t)row * DDIM;
  const float4* vin = reinterpret_cast<const float4*>(in + rowoff);

  float4 v0 = vin[lane];
  float4 v1 = vin[lane + 64u];
  float4 v2 = vin[lane + 128u];
  float4 v3 = vin[lane + 192u];
  float x[16] = {v0.x,v0.y,v0.z,v0.w, v1.x,v1.y,v1.z,v1.w,
                 v2.x,v2.y,v2.z,v2.w, v3.x,v3.y,v3.z,v3.w};

  // ---- row stats: in-wave reduction only
  float s = 0.0f, q = 0.0f;
  #pragma unroll
  for (int i = 0; i < 16; ++i) { s += x[i]; q = fmaf(x[i], x[i], q); }
  #pragma unroll
  for (int off = 32; off >= 1; off >>= 1) {
    s += __shfl_xor(s, off, 64);
    q += __shfl_xor(q, off, 64);
  }

  const float invD = 1.0f / (float)DDIM;
  const float mean = s * invD;
  float M2 = fmaf(-s, mean, q);                         // q - s^2/D
  M2 = fmaxf(M2, 0.0f);
  const float std_u = sqrtf(M2 * (1.0f / (DDIM - 1))); // unbiased (ddof=1)
  const float rstd  = rsqrtf(fmaf(M2, invD, 1e-5f));   // 1/sqrt(var_b + eps)
  const float hstd  = 0.5f * std_u;
  const float hmean = 0.5f * mean;
  const float noff  = -mean * rstd;

  // ---- per element: 2 threefry blocks -> 2 normals -> fused affine
  const uint32_t cb = row * (uint32_t)DDIM + lane * 4u;
  float o[16];
  #pragma unroll
  for (int i = 0; i < 16; ++i) {
    const uint32_t c = cb + (uint32_t)((i >> 2) << 8) + (uint32_t)(i & 3);
    const float ea = bits_to_normal(threefry_fold(k1a, k1b, c));
    const float eb = bits_to_normal(threefry_fold(k2a, k2b, c));
    const float normed = fmaf(x[i], rstd, noff);
    const float alpha  = fmaf(hstd, ea, 0.5f);   // 0.5*(1 + std*eps_a)
    const float beta   = fmaf(hstd, eb, hmean);  // 0.5*(mean + std*eps_b)
    o[i] = fmaf(alpha, normed, beta);
  }
  float4* vout = reinterpret_cast<float4*>(out + rowoff);
  vout[lane]        = make_float4(o[0],  o[1],  o[2],  o[3]);
  vout[lane + 64u]  = make_float4(o[4],  o[5],  o[6],  o[7]);
  vout[lane + 128u] = make_float4(o[8],  o[9],  o[10], o[11]);
  vout[lane + 192u] = make_float4(o[12], o[13], o[14], o[15]);
}

// ---------------- host side ----------------

static void tf_host(uint32_t k0, uint32_t k1, uint32_t c0, uint32_t c1,
                    uint32_t& o0, uint32_t& o1) {
  auto rot = [](uint32_t x, uint32_t r) { return (x << r) | (x >> (32u - r)); };
  const uint32_t ks[3] = {k0, k1, k0 ^ k1 ^ 0x1BD11BDAu};
  const uint32_t rots[2][4] = {{13u,15u,26u,6u},{17u,29u,16u,24u}};
  uint32_t x0 = c0 + k0, x1 = c1 + k1;
  for (int i = 0; i < 5; ++i) {
    const uint32_t* rr = rots[i & 1];
    for (int j = 0; j < 4; ++j) { x0 += x1; x1 = rot(x1, rr[j]); x1 ^= x0; }
    x0 += ks[(i + 1) % 3];
    x1 += ks[(i + 2) % 3] + (uint32_t)(i + 1);
  }
  o0 = x0; o1 = x1;
}

extern "C" void kernel_launch(void* const* d_in, const int* in_sizes, int n_in,
                              void* d_out, int out_size, void* d_ws, size_t ws_size,
                              hipStream_t stream) {
  const float* in = (const float*)d_in[0];
  float* out = (float*)d_out;

  // jax.random.key(42) -> (0,42); split (threefry_partitionable):
  // k1 = threefry((0,42),(0,0)), k2 = threefry((0,42),(0,1))
  uint32_t k1a, k1b, k2a, k2b;
  tf_host(0u, 42u, 0u, 0u, k1a, k1b);
  tf_host(0u, 42u, 0u, 1u, k2a, k2b);

  NormalAugmenter_kernel<<<NROWS / ROWS_PER_BLOCK, TPB, 0, stream>>>(
      in, out, k1a, k1b, k2a, k2b);
}